// Round 1
// baseline (1185.295 us; speedup 1.0000x reference)
//
#include <hip/hip_runtime.h>
#include <hip/hip_bf16.h>
#include <math.h>

#define B_SZ   64
#define N_TOK  4096
#define D_FEAT 256
#define K_SLOTS 6
#define H_DIM  64
#define N_IT   3

__device__ __forceinline__ float wave_reduce_sum(float v) {
    #pragma unroll
    for (int off = 32; off > 0; off >>= 1) v += __shfl_xor(v, off, 64);
    return v;
}

// ---------------- Stage 1: LN(features) -> k = f@Wk^T, v = f@Wv^T ----------------
// Block: 256 threads (4 waves). Each block handles 32 rows; each wave LNs its own
// 8 rows into LDS, then lane h computes k[row][h], v[row][h] for 8 rows with
// register blocking (Wk/Wv streamed once per block from L2).
__global__ __launch_bounds__(256) void ln_kv_kernel(
    const float* __restrict__ feat, const float* __restrict__ g,
    const float* __restrict__ bta, const float* __restrict__ Wk,
    const float* __restrict__ Wv, float* __restrict__ kout,
    float* __restrict__ vout)
{
    __shared__ float f_lds[32][260];   // +4 pad keeps float4 alignment, breaks bank stride
    const int t = threadIdx.x;
    const int lane = t & 63;
    const int wv = t >> 6;            // wave 0..3
    const long row0 = (long)blockIdx.x * 32;

    const float4 gg = *(const float4*)&g[lane * 4];
    const float4 bb = *(const float4*)&bta[lane * 4];

    #pragma unroll
    for (int r = 0; r < 8; ++r) {
        const long row = row0 + wv * 8 + r;
        const float4 x = *(const float4*)&feat[row * D_FEAT + lane * 4];
        float s1 = x.x + x.y + x.z + x.w;
        float s2 = x.x * x.x + x.y * x.y + x.z * x.z + x.w * x.w;
        s1 = wave_reduce_sum(s1);
        s2 = wave_reduce_sum(s2);
        const float m   = s1 * (1.0f / 256.0f);
        const float var = s2 * (1.0f / 256.0f) - m * m;
        const float inv = rsqrtf(var + 1e-5f);
        float4 y;
        y.x = (x.x - m) * inv * gg.x + bb.x;
        y.y = (x.y - m) * inv * gg.y + bb.y;
        y.z = (x.z - m) * inv * gg.z + bb.z;
        y.w = (x.w - m) * inv * gg.w + bb.w;
        *(float4*)&f_lds[wv * 8 + r][lane * 4] = y;
    }
    __syncthreads();

    const int h = lane;
    float acck[8], accv[8];
    #pragma unroll
    for (int r = 0; r < 8; ++r) { acck[r] = 0.0f; accv[r] = 0.0f; }

    const float* __restrict__ wkrow = Wk + h * D_FEAT;
    const float* __restrict__ wvrow = Wv + h * D_FEAT;
    for (int d = 0; d < D_FEAT; d += 4) {
        const float4 wk4 = *(const float4*)&wkrow[d];
        const float4 wv4 = *(const float4*)&wvrow[d];
        #pragma unroll
        for (int r = 0; r < 8; ++r) {
            const float4 f = *(const float4*)&f_lds[wv * 8 + r][d];
            acck[r] += f.x * wk4.x + f.y * wk4.y + f.z * wk4.z + f.w * wk4.w;
            accv[r] += f.x * wv4.x + f.y * wv4.y + f.z * wv4.z + f.w * wv4.w;
        }
    }
    #pragma unroll
    for (int r = 0; r < 8; ++r) {
        const long row = row0 + wv * 8 + r;
        kout[row * H_DIM + h] = acck[r];
        vout[row * H_DIM + h] = accv[r];
    }
}

// ---------------- slots init ----------------
__global__ void init_slots_kernel(const float* __restrict__ noise,
                                  const float* __restrict__ mu,
                                  const float* __restrict__ sigma,
                                  float* __restrict__ slots)
{
    const int i = blockIdx.x * 256 + threadIdx.x;
    if (i < B_SZ * K_SLOTS * H_DIM) {
        const int h = i & 63;
        slots[i] = mu[h] + sigma[h] * noise[i];
    }
}

// ---------------- per-iter: s=LN(slots), q=s@Wq^T, zero U/S ----------------
__global__ __launch_bounds__(64) void slot_q_kernel(
    const float* __restrict__ slots, const float* __restrict__ g,
    const float* __restrict__ bta, const float* __restrict__ Wq,
    float* __restrict__ q, float* __restrict__ U, float* __restrict__ S)
{
    __shared__ float s_lds[64];
    const int bk = blockIdx.x;     // b*6+k, 0..383
    const int lane = threadIdx.x;
    const float x = slots[bk * 64 + lane];
    const float s1 = wave_reduce_sum(x);
    const float s2 = wave_reduce_sum(x * x);
    const float m   = s1 * (1.0f / 64.0f);
    const float var = s2 * (1.0f / 64.0f) - m * m;
    const float inv = rsqrtf(var + 1e-5f);
    s_lds[lane] = (x - m) * inv * g[lane] + bta[lane];
    __syncthreads();
    float acc = 0.0f;
    const float* __restrict__ wrow = Wq + lane * 64;
    #pragma unroll 8
    for (int j = 0; j < 64; ++j) acc += s_lds[j] * wrow[j];
    q[bk * 64 + lane] = acc;
    U[bk * 64 + lane] = 0.0f;
    if (lane == 0) S[bk] = 0.0f;
}

// ---------------- per-iter: attn logits, softmax over slots, accumulate U,S ----------------
// grid (16, B): block handles 256 n for batch b, as 4 tiles of 64.
__global__ __launch_bounds__(256) void attn_kernel(
    const float* __restrict__ q, const float* __restrict__ kbuf,
    const float* __restrict__ vbuf, float* __restrict__ U,
    float* __restrict__ S)
{
    __shared__ float q_lds[K_SLOTS * 64];
    __shared__ float K_t[64][68];
    __shared__ float V_t[64][68];
    __shared__ float p_lds[K_SLOTS][64];

    const int t = threadIdx.x;
    const int b = blockIdx.y;
    const int chunk = blockIdx.x;

    for (int i = t; i < K_SLOTS * 64; i += 256) q_lds[i] = q[b * K_SLOTS * 64 + i];

    float Uacc[K_SLOTS], Sacc[K_SLOTS];
    #pragma unroll
    for (int k = 0; k < K_SLOTS; ++k) { Uacc[k] = 0.0f; Sacc[k] = 0.0f; }

    const int n_loc = t >> 2, sub = t & 3;   // phase A mapping
    const int h = t & 63,   wv = t >> 6;     // phase B mapping

    for (int tile = 0; tile < 4; ++tile) {
        __syncthreads();
        const long nbase = (long)b * N_TOK + chunk * 256 + tile * 64;
        #pragma unroll
        for (int i = 0; i < 16; ++i) {
            const int e = i * 256 + t;
            const int row = e >> 6, col = e & 63;
            K_t[row][col] = kbuf[(nbase + row) * 64 + col];
            V_t[row][col] = vbuf[(nbase + row) * 64 + col];
        }
        __syncthreads();

        // phase A: logits + softmax over k (4 threads/n, 16 h each)
        float part[K_SLOTS] = {0, 0, 0, 0, 0, 0};
        for (int hh = sub * 16; hh < sub * 16 + 16; ++hh) {
            const float kv = K_t[n_loc][hh];
            #pragma unroll
            for (int k = 0; k < K_SLOTS; ++k) part[k] += q_lds[k * 64 + hh] * kv;
        }
        #pragma unroll
        for (int k = 0; k < K_SLOTS; ++k) {
            part[k] += __shfl_xor(part[k], 1, 64);
            part[k] += __shfl_xor(part[k], 2, 64);
        }
        float l[K_SLOTS], mx;
        #pragma unroll
        for (int k = 0; k < K_SLOTS; ++k) l[k] = part[k] * 0.125f;
        mx = l[0];
        #pragma unroll
        for (int k = 1; k < K_SLOTS; ++k) mx = fmaxf(mx, l[k]);
        float e[K_SLOTS], ssum = 0.0f;
        #pragma unroll
        for (int k = 0; k < K_SLOTS; ++k) { e[k] = __expf(l[k] - mx); ssum += e[k]; }
        const float rs = 1.0f / ssum;
        if (sub == 0) {
            #pragma unroll
            for (int k = 0; k < K_SLOTS; ++k) {
                const float p = e[k] * rs;
                p_lds[k][n_loc] = p;
                Sacc[k] += p;
            }
        }
        __syncthreads();

        // phase B: U[k][h] += sum_n p[k][n] * V[n][h]  (wave wv covers 16 n)
        for (int n = wv * 16; n < wv * 16 + 16; ++n) {
            const float vval = V_t[n][h];
            #pragma unroll
            for (int k = 0; k < K_SLOTS; ++k) Uacc[k] += p_lds[k][n] * vval;
        }
    }

    #pragma unroll
    for (int k = 0; k < K_SLOTS; ++k)
        atomicAdd(&U[((long)b * K_SLOTS + k) * 64 + h], Uacc[k]);
    if (sub == 0) {
        #pragma unroll
        for (int k = 0; k < K_SLOTS; ++k)
            atomicAdd(&S[b * K_SLOTS + k], Sacc[k]);
    }
}

// ---------------- per-iter: updates=U/(S+eps), GRU, LN, MLP, residual ----------------
__global__ __launch_bounds__(64) void update_kernel(
    const float* __restrict__ U, const float* __restrict__ S,
    float* __restrict__ slots,
    const float* __restrict__ W_ih, const float* __restrict__ W_hh,
    const float* __restrict__ b_ih, const float* __restrict__ b_hh,
    const float* __restrict__ g_mlp, const float* __restrict__ b_mlp,
    const float* __restrict__ W1, const float* __restrict__ b1,
    const float* __restrict__ W2, const float* __restrict__ b2,
    float* __restrict__ out, int write_out)
{
    __shared__ float x_lds[64];
    __shared__ float h_lds[64];
    __shared__ float m_lds[64];
    __shared__ float r_lds[128];
    const int bk = blockIdx.x, lane = threadIdx.x;

    const float u  = U[bk * 64 + lane] / (S[bk] + 1e-8f);
    const float hp = slots[bk * 64 + lane];
    x_lds[lane] = u;
    h_lds[lane] = hp;
    __syncthreads();

    float ir = b_ih[lane], iz = b_ih[64 + lane], inn = b_ih[128 + lane];
    float hr = b_hh[lane], hz = b_hh[64 + lane], hn  = b_hh[128 + lane];
    const float* __restrict__ wr = W_ih + lane * 64;
    const float* __restrict__ wz = W_ih + (64 + lane) * 64;
    const float* __restrict__ wn = W_ih + (128 + lane) * 64;
    const float* __restrict__ vr = W_hh + lane * 64;
    const float* __restrict__ vz = W_hh + (64 + lane) * 64;
    const float* __restrict__ vn = W_hh + (128 + lane) * 64;
    #pragma unroll 4
    for (int j = 0; j < 64; ++j) {
        const float xj = x_lds[j], hj = h_lds[j];
        ir += wr[j] * xj; iz += wz[j] * xj; inn += wn[j] * xj;
        hr += vr[j] * hj; hz += vz[j] * hj; hn  += vn[j] * hj;
    }
    const float r = 1.0f / (1.0f + __expf(-(ir + hr)));
    const float z = 1.0f / (1.0f + __expf(-(iz + hz)));
    const float nn = tanhf(inn + r * hn);
    const float hnew = (1.0f - z) * nn + z * hp;

    const float s1 = wave_reduce_sum(hnew);
    const float s2 = wave_reduce_sum(hnew * hnew);
    const float m   = s1 * (1.0f / 64.0f);
    const float var = s2 * (1.0f / 64.0f) - m * m;
    const float inv = rsqrtf(var + 1e-5f);
    m_lds[lane] = (hnew - m) * inv * g_mlp[lane] + b_mlp[lane];
    __syncthreads();

    float a1 = b1[lane], a2 = b1[64 + lane];
    const float* __restrict__ w1a = W1 + lane * 64;
    const float* __restrict__ w1b = W1 + (64 + lane) * 64;
    #pragma unroll 4
    for (int j = 0; j < 64; ++j) {
        const float mj = m_lds[j];
        a1 += w1a[j] * mj;
        a2 += w1b[j] * mj;
    }
    r_lds[lane] = fmaxf(a1, 0.0f);
    r_lds[64 + lane] = fmaxf(a2, 0.0f);
    __syncthreads();

    float o = b2[lane];
    const float* __restrict__ w2 = W2 + lane * 128;
    #pragma unroll 4
    for (int c = 0; c < 128; ++c) o += w2[c] * r_lds[c];

    const float res = hnew + o;
    slots[bk * 64 + lane] = res;
    if (write_out) out[bk * 64 + lane] = res;
}

extern "C" void kernel_launch(void* const* d_in, const int* in_sizes, int n_in,
                              void* d_out, int out_size, void* d_ws, size_t ws_size,
                              hipStream_t stream) {
    const float* feat      = (const float*)d_in[0];
    const float* noise     = (const float*)d_in[1];
    const float* mu        = (const float*)d_in[2];
    const float* sigma     = (const float*)d_in[3];
    const float* ln_feat_g = (const float*)d_in[4];
    const float* ln_feat_b = (const float*)d_in[5];
    const float* ln_slot_g = (const float*)d_in[6];
    const float* ln_slot_b = (const float*)d_in[7];
    const float* ln_mlp_g  = (const float*)d_in[8];
    const float* ln_mlp_b  = (const float*)d_in[9];
    const float* Wk        = (const float*)d_in[10];
    const float* Wv        = (const float*)d_in[11];
    const float* Wq        = (const float*)d_in[12];
    const float* W_ih      = (const float*)d_in[13];
    const float* W_hh      = (const float*)d_in[14];
    const float* b_ih      = (const float*)d_in[15];
    const float* b_hh      = (const float*)d_in[16];
    const float* W1        = (const float*)d_in[17];
    const float* b1        = (const float*)d_in[18];
    const float* W2        = (const float*)d_in[19];
    const float* b2        = (const float*)d_in[20];
    float* out = (float*)d_out;

    float* ws    = (float*)d_ws;
    float* kbuf  = ws;
    float* vbuf  = kbuf + (size_t)B_SZ * N_TOK * H_DIM;
    float* slots = vbuf + (size_t)B_SZ * N_TOK * H_DIM;
    float* qb    = slots + B_SZ * K_SLOTS * H_DIM;
    float* Ub    = qb + B_SZ * K_SLOTS * H_DIM;
    float* Sb    = Ub + B_SZ * K_SLOTS * H_DIM;

    hipLaunchKernelGGL(ln_kv_kernel, dim3(B_SZ * N_TOK / 32), dim3(256), 0, stream,
                       feat, ln_feat_g, ln_feat_b, Wk, Wv, kbuf, vbuf);
    hipLaunchKernelGGL(init_slots_kernel, dim3(96), dim3(256), 0, stream,
                       noise, mu, sigma, slots);
    for (int it = 0; it < N_IT; ++it) {
        hipLaunchKernelGGL(slot_q_kernel, dim3(384), dim3(64), 0, stream,
                           slots, ln_slot_g, ln_slot_b, Wq, qb, Ub, Sb);
        hipLaunchKernelGGL(attn_kernel, dim3(16, B_SZ), dim3(256), 0, stream,
                           qb, kbuf, vbuf, Ub, Sb);
        hipLaunchKernelGGL(update_kernel, dim3(384), dim3(64), 0, stream,
                           Ub, Sb, slots, W_ih, W_hh, b_ih, b_hh,
                           ln_mlp_g, ln_mlp_b, W1, b1, W2, b2,
                           out, (it == N_IT - 1) ? 1 : 0);
    }
}

// Round 2
// 575.331 us; speedup vs baseline: 2.0602x; 2.0602x over previous
//
#include <hip/hip_runtime.h>
#include <hip/hip_bf16.h>
#include <math.h>

#define B_SZ    64
#define N_TOK   4096
#define D_FEAT  256
#define K_SLOTS 6
#define H_DIM   64
#define N_IT    3
#define CHUNKS  8
#define LNKV_BLOCKS 512
#define TILES_PER_BLOCK 8   // 512 blocks * 8 tiles * 64 rows = 262144 rows

typedef __attribute__((ext_vector_type(8))) __bf16 bf16x8;
typedef __attribute__((ext_vector_type(4))) __bf16 bf16x4;
typedef __attribute__((ext_vector_type(4))) float  f32x4v;

__device__ __forceinline__ float wave_reduce_sum(float v) {
    #pragma unroll
    for (int off = 32; off > 0; off >>= 1) v += __shfl_xor(v, off, 64);
    return v;
}
__device__ __forceinline__ float bflo(unsigned u) { return __builtin_bit_cast(float, (unsigned)(u << 16)); }
__device__ __forceinline__ float bfhi(unsigned u) { return __builtin_bit_cast(float, (unsigned)(u & 0xffff0000u)); }

// ================= prep: W->bf16 fragment order, slots init, transposed small weights ==========
__global__ __launch_bounds__(256) void prep_kernel(
    const float* __restrict__ Wk, const float* __restrict__ Wv,
    const float* __restrict__ noise, const float* __restrict__ mu,
    const float* __restrict__ sigma, const float* __restrict__ Wq,
    const float* __restrict__ W_ih, const float* __restrict__ W_hh,
    const float* __restrict__ W1, const float* __restrict__ W2,
    __bf16* __restrict__ Wfrag, float* __restrict__ slots,
    float* __restrict__ WqT, float* __restrict__ WihT, float* __restrict__ WhhT,
    float* __restrict__ W1T, float* __restrict__ W2T)
{
    const int tg = blockIdx.x * 256 + threadIdx.x;
    if (tg < 4096) {
        // W fragment order: [ct][ks][lane][j], value = Wkv[ct*16+(lane&15)][(lane>>4)*8+ks*32+j]
        const int chunk = tg >> 6, lane = tg & 63;
        const int ct = chunk >> 3, ks = chunk & 7;
        const int outr = ct * 16 + (lane & 15);
        const int dbase = (lane >> 4) * 8 + ks * 32;
        const float* srcw = (outr < 64) ? &Wk[outr * 256] : &Wv[(outr - 64) * 256];
        bf16x8 w8;
        #pragma unroll
        for (int j = 0; j < 8; ++j) w8[j] = (__bf16)srcw[dbase + j];
        *(bf16x8*)&Wfrag[(size_t)tg * 8] = w8;
    } else if (tg < 4096 + 24576) {
        const int i = tg - 4096;
        const int hh = i & 63;
        slots[i] = mu[hh] + sigma[hh] * noise[i];
    } else if (tg < 32768) {
        const int i = tg - 28672;                 // WqT[j*64+h] = Wq[h*64+j]
        WqT[i] = Wq[(i & 63) * 64 + (i >> 6)];
    } else if (tg < 45056) {
        const int i = tg - 32768;                 // WihT[j*192+r] = W_ih[r*64+j]
        WihT[i] = W_ih[(i % 192) * 64 + (i / 192)];
    } else if (tg < 57344) {
        const int i = tg - 45056;
        WhhT[i] = W_hh[(i % 192) * 64 + (i / 192)];
    } else if (tg < 65536) {
        const int i = tg - 57344;                 // W1T[j*128+r] = W1[r*64+j]
        W1T[i] = W1[(i & 127) * 64 + (i >> 7)];
    } else if (tg < 73728) {
        const int i = tg - 65536;                 // W2T[c*64+h] = W2[h*128+c]
        W2T[i] = W2[(i & 63) * 128 + (i >> 6)];
    }
}

// ================= Stage 1: fused LN + MFMA GEMM -> kv bf16 [row][128] ==========
// 512 blocks, 4 waves each; W fragments resident in LDS per block; each wave owns
// 16 rows per tile (LN rows, A rows, C rows all wave-private -> no barriers in loop).
__global__ __launch_bounds__(256, 1) void ln_kv_mfma(
    const float* __restrict__ feat, const float* __restrict__ g,
    const float* __restrict__ bta, const __bf16* __restrict__ Wfrag,
    __bf16* __restrict__ kv)
{
    __shared__ __align__(16) __bf16 W_lds[32768];      // 64 KB, fragment order
    __shared__ __align__(16) __bf16 A_lds[64][264];    // row-major, pad for 16B align
    __shared__ __align__(16) __bf16 C_lds[64][136];    // repack buffer

    const int t = threadIdx.x;
    const int lane = t & 63;
    const int w = t >> 6;
    const int m15 = lane & 15;
    const int q4 = lane >> 4;

    {   // stage W fragments (straight 64KB copy)
        const uint4* src = (const uint4*)Wfrag;
        uint4* dst = (uint4*)W_lds;
        #pragma unroll
        for (int i = 0; i < 16; ++i) dst[i * 256 + t] = src[i * 256 + t];
    }
    __syncthreads();

    const float4 gg = *(const float4*)&g[lane * 4];
    const float4 bb = *(const float4*)&bta[lane * 4];

    float4 x[16];
    {   // prefetch tile 0 (wave-private rows)
        const size_t row0 = (size_t)blockIdx.x * TILES_PER_BLOCK * 64 + w * 16;
        #pragma unroll
        for (int r = 0; r < 16; ++r)
            x[r] = *(const float4*)&feat[(row0 + r) * D_FEAT + lane * 4];
    }

    for (int tile = 0; tile < TILES_PER_BLOCK; ++tile) {
        const size_t tile_row0 = (size_t)blockIdx.x * TILES_PER_BLOCK * 64 + (size_t)tile * 64;

        // LN + bf16 convert + write A_lds
        #pragma unroll
        for (int r = 0; r < 16; ++r) {
            float s1 = x[r].x + x[r].y + x[r].z + x[r].w;
            float s2 = x[r].x * x[r].x + x[r].y * x[r].y + x[r].z * x[r].z + x[r].w * x[r].w;
            s1 = wave_reduce_sum(s1);
            s2 = wave_reduce_sum(s2);
            const float m = s1 * (1.0f / 256.0f);
            const float inv = rsqrtf(s2 * (1.0f / 256.0f) - m * m + 1e-5f);
            bf16x4 y;
            y[0] = (__bf16)((x[r].x - m) * inv * gg.x + bb.x);
            y[1] = (__bf16)((x[r].y - m) * inv * gg.y + bb.y);
            y[2] = (__bf16)((x[r].z - m) * inv * gg.z + bb.z);
            y[3] = (__bf16)((x[r].w - m) * inv * gg.w + bb.w);
            *(bf16x4*)&A_lds[w * 16 + r][lane * 4] = y;
        }

        // prefetch next tile while MFMA runs
        if (tile + 1 < TILES_PER_BLOCK) {
            const size_t row0 = tile_row0 + 64 + w * 16;
            #pragma unroll
            for (int r = 0; r < 16; ++r)
                x[r] = *(const float4*)&feat[(row0 + r) * D_FEAT + lane * 4];
        }

        // A fragments (wave-private rows)
        bf16x8 af[8];
        #pragma unroll
        for (int ks = 0; ks < 8; ++ks)
            af[ks] = *(const bf16x8*)&A_lds[w * 16 + m15][q4 * 8 + ks * 32];

        f32x4v acc[8];
        #pragma unroll
        for (int ct = 0; ct < 8; ++ct) acc[ct] = (f32x4v){0.f, 0.f, 0.f, 0.f};

        #pragma unroll
        for (int ks = 0; ks < 8; ++ks) {
            #pragma unroll
            for (int ct = 0; ct < 8; ++ct) {
                const bf16x8 bfr = *(const bf16x8*)&W_lds[((ct * 8 + ks) * 64 + lane) * 8];
                acc[ct] = __builtin_amdgcn_mfma_f32_16x16x32_bf16(af[ks], bfr, acc[ct], 0, 0, 0);
            }
        }

        // C repack (wave-private rows) + coalesced bf16 store
        #pragma unroll
        for (int ct = 0; ct < 8; ++ct) {
            #pragma unroll
            for (int reg = 0; reg < 4; ++reg)
                C_lds[w * 16 + q4 * 4 + reg][ct * 16 + m15] = (__bf16)acc[ct][reg];
        }
        const int lr = w * 16 + (lane >> 2);
        const int seg = lane & 3;
        __bf16* dstg = kv + (tile_row0 + lr) * 128 + seg * 32;
        #pragma unroll
        for (int u = 0; u < 4; ++u) {
            const uint4 val = *(const uint4*)&C_lds[lr][seg * 32 + u * 8];
            *(uint4*)&dstg[u * 8] = val;
        }
    }
}

// ================= initial q from slots ==========
__global__ __launch_bounds__(64) void slot_q0(
    const float* __restrict__ slots, const float* __restrict__ g,
    const float* __restrict__ bta, const float* __restrict__ WqT,
    float* __restrict__ qb)
{
    __shared__ float s_lds[64];
    const int bk = blockIdx.x, h = threadIdx.x;
    const float xv = slots[bk * 64 + h];
    const float s1 = wave_reduce_sum(xv);
    const float s2 = wave_reduce_sum(xv * xv);
    const float m = s1 * (1.0f / 64.0f);
    const float inv = rsqrtf(s2 * (1.0f / 64.0f) - m * m + 1e-5f);
    s_lds[h] = (xv - m) * inv * g[h] + bta[h];
    __syncthreads();
    float acc = 0.f;
    #pragma unroll 8
    for (int j = 0; j < 64; ++j) acc += WqT[j * 64 + h] * s_lds[j];
    qb[bk * 64 + h] = acc;
}

// ================= attention: logits + slot-softmax + partial U,S (no atomics) ==========
__global__ __launch_bounds__(256) void attn_kernel(
    const float* __restrict__ qb, const __bf16* __restrict__ kv,
    float* __restrict__ U_part, float* __restrict__ S_part)
{
    __shared__ float q_lds[K_SLOTS * 64];
    __shared__ __align__(16) float KVt[64][130];
    __shared__ float p_lds[K_SLOTS][64];
    __shared__ float U_red[4][K_SLOTS][64];
    __shared__ float S_red[4][K_SLOTS];

    const int t = threadIdx.x;
    const int b = blockIdx.y;
    const int chunk = blockIdx.x;
    const int lane = t & 63;
    const int w = t >> 6;
    const int n_loc = t >> 2, sub = t & 3;
    const int h = lane;

    for (int i = t; i < K_SLOTS * 64; i += 256) q_lds[i] = qb[b * K_SLOTS * 64 + i];

    float Uacc[K_SLOTS] = {0, 0, 0, 0, 0, 0};
    float Sacc[K_SLOTS] = {0, 0, 0, 0, 0, 0};

    for (int tile = 0; tile < 8; ++tile) {
        __syncthreads();   // guard KVt/p_lds reuse (also covers q_lds on tile 0)
        const size_t n0 = (size_t)b * N_TOK + (size_t)chunk * (N_TOK / CHUNKS) + tile * 64;
        {   // stage: wave w stages 64B segment w of each of 64 rows (bf16 -> f32)
            const uint4* src = (const uint4*)&kv[(n0 + lane) * 128 + w * 32];
            float2* drow = (float2*)&KVt[lane][w * 32];
            #pragma unroll
            for (int u = 0; u < 4; ++u) {
                const uint4 pk = src[u];
                drow[u * 4 + 0] = make_float2(bflo(pk.x), bfhi(pk.x));
                drow[u * 4 + 1] = make_float2(bflo(pk.y), bfhi(pk.y));
                drow[u * 4 + 2] = make_float2(bflo(pk.z), bfhi(pk.z));
                drow[u * 4 + 3] = make_float2(bflo(pk.w), bfhi(pk.w));
            }
        }
        __syncthreads();

        // phase A: logits (4 subs x 16 h each), softmax over slots
        float part[K_SLOTS] = {0, 0, 0, 0, 0, 0};
        #pragma unroll
        for (int i = 0; i < 16; ++i) {
            const float kvv = KVt[n_loc][sub * 16 + i];
            #pragma unroll
            for (int k = 0; k < K_SLOTS; ++k) part[k] += q_lds[k * 64 + sub * 16 + i] * kvv;
        }
        #pragma unroll
        for (int k = 0; k < K_SLOTS; ++k) {
            part[k] += __shfl_xor(part[k], 1, 64);
            part[k] += __shfl_xor(part[k], 2, 64);
        }
        float mx = part[0];
        #pragma unroll
        for (int k = 1; k < K_SLOTS; ++k) mx = fmaxf(mx, part[k]);
        float e[K_SLOTS], ssum = 0.f;
        #pragma unroll
        for (int k = 0; k < K_SLOTS; ++k) { e[k] = __expf((part[k] - mx) * 0.125f); ssum += e[k]; }
        // NOTE: scale must apply before max-subtract; redo correctly:
        // (recompute with scaled logits)
        mx = part[0] * 0.125f;
        #pragma unroll
        for (int k = 1; k < K_SLOTS; ++k) mx = fmaxf(mx, part[k] * 0.125f);
        ssum = 0.f;
        #pragma unroll
        for (int k = 0; k < K_SLOTS; ++k) { e[k] = __expf(part[k] * 0.125f - mx); ssum += e[k]; }
        const float rs = 1.0f / ssum;
        if (sub == 0) {
            #pragma unroll
            for (int k = 0; k < K_SLOTS; ++k) {
                const float p = e[k] * rs;
                p_lds[k][n_loc] = p;
                Sacc[k] += p;
            }
        }
        __syncthreads();

        // phase B: U[k][h] partial over this wave's 16 n
        for (int n = w * 16; n < w * 16 + 16; ++n) {
            const float vv = KVt[n][64 + h];
            #pragma unroll
            for (int k = 0; k < K_SLOTS; ++k) Uacc[k] += p_lds[k][n] * vv;
        }
    }

    #pragma unroll
    for (int k = 0; k < K_SLOTS; ++k) U_red[w][k][h] = Uacc[k];
    #pragma unroll
    for (int k = 0; k < K_SLOTS; ++k) {
        const float s = wave_reduce_sum(Sacc[k]);
        if (lane == 0) S_red[w][k] = s;
    }
    __syncthreads();
    for (int idx = t; idx < K_SLOTS * 64; idx += 256) {
        const int k = idx >> 6, hh = idx & 63;
        const float s = U_red[0][k][hh] + U_red[1][k][hh] + U_red[2][k][hh] + U_red[3][k][hh];
        U_part[(((size_t)b * CHUNKS + chunk) * K_SLOTS + k) * 64 + hh] = s;
    }
    if (t < K_SLOTS) {
        const float s = S_red[0][t] + S_red[1][t] + S_red[2][t] + S_red[3][t];
        S_part[((size_t)b * CHUNKS + chunk) * K_SLOTS + t] = s;
    }
}

// ================= reduce partials + GRU + LN + MLP + residual (+ next q) ==========
__global__ __launch_bounds__(64) void update_kernel(
    const float* __restrict__ U_part, const float* __restrict__ S_part,
    float* __restrict__ slots,
    const float* __restrict__ WihT, const float* __restrict__ WhhT,
    const float* __restrict__ b_ih, const float* __restrict__ b_hh,
    const float* __restrict__ g_mlp, const float* __restrict__ b_mlp,
    const float* __restrict__ W1T, const float* __restrict__ b1,
    const float* __restrict__ W2T, const float* __restrict__ b2,
    const float* __restrict__ g_slot, const float* __restrict__ b_slot,
    const float* __restrict__ WqT, float* __restrict__ qb,
    float* __restrict__ out, int last)
{
    __shared__ float x_lds[64], h_lds[64], m_lds[64], r_lds[128];
    const int bk = blockIdx.x, h = threadIdx.x;
    const int b = bk / K_SLOTS, k = bk % K_SLOTS;

    float Us = 0.f, Ss = 0.f;
    #pragma unroll
    for (int c = 0; c < CHUNKS; ++c)
        Us += U_part[(((size_t)b * CHUNKS + c) * K_SLOTS + k) * 64 + h];
    #pragma unroll
    for (int c = 0; c < CHUNKS; ++c)
        Ss += S_part[((size_t)b * CHUNKS + c) * K_SLOTS + k];

    const float u = Us / (Ss + 1e-8f);
    const float hp = slots[bk * 64 + h];
    x_lds[h] = u;
    h_lds[h] = hp;
    __syncthreads();

    float ir = b_ih[h], iz = b_ih[64 + h], inn = b_ih[128 + h];
    float hr = b_hh[h], hz = b_hh[64 + h], hn = b_hh[128 + h];
    #pragma unroll 4
    for (int j = 0; j < 64; ++j) {
        const float xj = x_lds[j], hj = h_lds[j];
        const float* wi = &WihT[j * 192];
        const float* wh = &WhhT[j * 192];
        ir += wi[h] * xj; iz += wi[64 + h] * xj; inn += wi[128 + h] * xj;
        hr += wh[h] * hj; hz += wh[64 + h] * hj; hn += wh[128 + h] * hj;
    }
    const float r = 1.0f / (1.0f + __expf(-(ir + hr)));
    const float z = 1.0f / (1.0f + __expf(-(iz + hz)));
    const float nn = tanhf(inn + r * hn);
    const float hnew = (1.0f - z) * nn + z * hp;

    const float s1 = wave_reduce_sum(hnew);
    const float s2 = wave_reduce_sum(hnew * hnew);
    const float m = s1 * (1.0f / 64.0f);
    const float inv = rsqrtf(s2 * (1.0f / 64.0f) - m * m + 1e-5f);
    m_lds[h] = (hnew - m) * inv * g_mlp[h] + b_mlp[h];
    __syncthreads();

    float a1 = b1[h], a2 = b1[64 + h];
    #pragma unroll 4
    for (int j = 0; j < 64; ++j) {
        const float mj = m_lds[j];
        a1 += W1T[j * 128 + h] * mj;
        a2 += W1T[j * 128 + 64 + h] * mj;
    }
    r_lds[h] = fmaxf(a1, 0.f);
    r_lds[64 + h] = fmaxf(a2, 0.f);
    __syncthreads();

    float o = b2[h];
    #pragma unroll 4
    for (int c = 0; c < 128; ++c) o += W2T[c * 64 + h] * r_lds[c];

    const float res = hnew + o;
    slots[bk * 64 + h] = res;
    if (last) {
        out[bk * 64 + h] = res;
    } else {
        // fused q for next iteration
        const float t1 = wave_reduce_sum(res);
        const float t2 = wave_reduce_sum(res * res);
        const float mm = t1 * (1.0f / 64.0f);
        const float ii = rsqrtf(t2 * (1.0f / 64.0f) - mm * mm + 1e-5f);
        m_lds[h] = (res - mm) * ii * g_slot[h] + b_slot[h];
        __syncthreads();
        float qv = 0.f;
        #pragma unroll 8
        for (int j = 0; j < 64; ++j) qv += WqT[j * 64 + h] * m_lds[j];
        qb[bk * 64 + h] = qv;
    }
}

extern "C" void kernel_launch(void* const* d_in, const int* in_sizes, int n_in,
                              void* d_out, int out_size, void* d_ws, size_t ws_size,
                              hipStream_t stream) {
    const float* feat      = (const float*)d_in[0];
    const float* noise     = (const float*)d_in[1];
    const float* mu        = (const float*)d_in[2];
    const float* sigma     = (const float*)d_in[3];
    const float* ln_feat_g = (const float*)d_in[4];
    const float* ln_feat_b = (const float*)d_in[5];
    const float* ln_slot_g = (const float*)d_in[6];
    const float* ln_slot_b = (const float*)d_in[7];
    const float* ln_mlp_g  = (const float*)d_in[8];
    const float* ln_mlp_b  = (const float*)d_in[9];
    const float* Wk        = (const float*)d_in[10];
    const float* Wv        = (const float*)d_in[11];
    const float* Wq        = (const float*)d_in[12];
    const float* W_ih      = (const float*)d_in[13];
    const float* W_hh      = (const float*)d_in[14];
    const float* b_ih      = (const float*)d_in[15];
    const float* b_hh      = (const float*)d_in[16];
    const float* W1        = (const float*)d_in[17];
    const float* b1        = (const float*)d_in[18];
    const float* W2        = (const float*)d_in[19];
    const float* b2        = (const float*)d_in[20];
    float* out = (float*)d_out;

    char* p = (char*)d_ws;
    __bf16* kv    = (__bf16*)p;                 p += (size_t)B_SZ * N_TOK * 128 * 2;  // 64 MB
    __bf16* Wfrag = (__bf16*)p;                 p += 32768 * 2;
    float* slots  = (float*)p;                  p += 24576 * 4;
    float* qb     = (float*)p;                  p += 24576 * 4;
    float* U_part = (float*)p;                  p += (size_t)B_SZ * CHUNKS * K_SLOTS * 64 * 4;
    float* S_part = (float*)p;                  p += (size_t)B_SZ * CHUNKS * K_SLOTS * 4;
    float* WqT    = (float*)p;                  p += 4096 * 4;
    float* WihT   = (float*)p;                  p += 12288 * 4;
    float* WhhT   = (float*)p;                  p += 12288 * 4;
    float* W1T    = (float*)p;                  p += 8192 * 4;
    float* W2T    = (float*)p;                  p += 8192 * 4;

    hipLaunchKernelGGL(prep_kernel, dim3(288), dim3(256), 0, stream,
                       Wk, Wv, noise, mu, sigma, Wq, W_ih, W_hh, W1, W2,
                       Wfrag, slots, WqT, WihT, WhhT, W1T, W2T);
    hipLaunchKernelGGL(ln_kv_mfma, dim3(LNKV_BLOCKS), dim3(256), 0, stream,
                       feat, ln_feat_g, ln_feat_b, Wfrag, kv);
    hipLaunchKernelGGL(slot_q0, dim3(384), dim3(64), 0, stream,
                       slots, ln_slot_g, ln_slot_b, WqT, qb);
    for (int it = 0; it < N_IT; ++it) {
        hipLaunchKernelGGL(attn_kernel, dim3(CHUNKS, B_SZ), dim3(256), 0, stream,
                           qb, kv, U_part, S_part);
        hipLaunchKernelGGL(update_kernel, dim3(384), dim3(64), 0, stream,
                           U_part, S_part, slots, WihT, WhhT, b_ih, b_hh,
                           ln_mlp_g, ln_mlp_b, W1T, b1, W2T, b2,
                           ln_slot_g, ln_slot_b, WqT, qb,
                           out, (it == N_IT - 1) ? 1 : 0);
    }
}